// Round 8
// baseline (192.815 us; speedup 1.0000x reference)
//
#include <hip/hip_runtime.h>

#define NK 1024
#define DD 48              // 4*4*3 floats per code / per block
#define NL (512 * 512)     // 262144 blocks
#define NTILE 32           // 32 code-tiles of 32 codes

// workspace layout (float offsets)
#define WS_CNORM 0
#define WS_BFRAG 1024
#define FRAGS_PER_LEVEL (32 * 3 * 64)     // tiles * ksteps * lanes = 6144 frags
#define WS_FLOATS (1024 + 3 * FRAGS_PER_LEVEL * 4)

typedef __attribute__((ext_vector_type(8)))  short bf16x8;
typedef __attribute__((ext_vector_type(16))) float f32x16;

// fp32 -> bf16 bits, round-to-nearest-even (finite inputs)
__device__ __forceinline__ unsigned int rneb(float x) {
    unsigned int u = __float_as_uint(x);
    return (u + 0x7FFFu + ((u >> 16) & 1u)) >> 16;
}
__device__ __forceinline__ float bftof(unsigned int b) {
    return __uint_as_float(b << 16);
}
// 3-term bf16 split: x = h + m + l (residual splits exact; l trunc ~2^-27 rel)
__device__ __forceinline__ void split3(float x, unsigned int& hb, unsigned int& mb, unsigned int& lb) {
    hb = rneb(x);
    float r1 = x - bftof(hb);
    mb = rneb(r1);
    float r2 = r1 - bftof(mb);
    lb = rneb(r2);
}

// cnorm[k] = sum_j cb[k][j]^2 (fp32 sequential FMA)
__global__ void vq_cnorm_kernel(const float* __restrict__ cb, float* __restrict__ cnorm) {
    int k = blockIdx.x * blockDim.x + threadIdx.x;
    if (k >= NK) return;
    const float* row = cb + k * DD;
    float s = 0.0f;
#pragma unroll
    for (int j = 0; j < DD; ++j) s = fmaf(row[j], row[j], s);
    cnorm[k] = s;
}

// B prep: pack codebook into MFMA B-fragments for levels h/m/l.
// Frag (t, s, lane): code = t*32 + (lane&31), j = s*16 + (lane>>5)*8 + e.
__global__ void vq_bprep_kernel(const float* __restrict__ cb, float* __restrict__ ws) {
    int tid = blockIdx.x * blockDim.x + threadIdx.x;
    if (tid >= FRAGS_PER_LEVEL) return;
    int lane = tid & 63;
    int s    = (tid >> 6) % 3;
    int t    = tid / (3 * 64);
    int col = lane & 31, lh = lane >> 5;
    int code = t * 32 + col;
    int j0 = s * 16 + lh * 8;
    const float* src = cb + code * DD + j0;
    bf16x8 vh, vm, vl;
#pragma unroll
    for (int e = 0; e < 8; ++e) {
        unsigned int hb, mb, lb;
        split3(src[e], hb, mb, lb);
        vh[e] = (short)hb; vm[e] = (short)mb; vl[e] = (short)lb;
    }
    bf16x8* base = (bf16x8*)(ws + WS_BFRAG);
    int fi = (t * 3 + s) * 64 + lane;
    base[0 * FRAGS_PER_LEVEL + fi] = vh;
    base[1 * FRAGS_PER_LEVEL + fi] = vm;
    base[2 * FRAGS_PER_LEVEL + fi] = vl;
}

#define MFMA __builtin_amdgcn_mfma_f32_32x32x16_bf16

// Load tile T's 9 B-fragments + cnorm slice into named ping-pong buffer BUF.
#define LOADB(BUF, T) do {                                              \
        const int fi_ = ((T) * 3) * 64 + lane;                          \
        BUF##h0 = bfrag[fi_];                                           \
        BUF##h1 = bfrag[fi_ + 64];                                      \
        BUF##h2 = bfrag[fi_ + 128];                                     \
        BUF##m0 = bfrag[FRAGS_PER_LEVEL + fi_];                         \
        BUF##m1 = bfrag[FRAGS_PER_LEVEL + fi_ + 64];                    \
        BUF##m2 = bfrag[FRAGS_PER_LEVEL + fi_ + 128];                   \
        BUF##l0 = bfrag[2 * FRAGS_PER_LEVEL + fi_];                     \
        BUF##l1 = bfrag[2 * FRAGS_PER_LEVEL + fi_ + 64];                \
        BUF##l2 = bfrag[2 * FRAGS_PER_LEVEL + fi_ + 128];               \
        BUF##cn = cnorm[(T) * 32 + col];                                \
    } while (0)

// 36 MFMAs (6 products x 3 ksteps, small->large, same order as R7) + epilogue.
#define COMPUTE(BUF, T) do {                                            \
        f32x16 a0, a1;                                                  \
        _Pragma("unroll")                                               \
        for (int q = 0; q < 16; ++q) { a0[q] = 0.0f; a1[q] = 0.0f; }    \
        a0 = MFMA(Am[0][0], BUF##m0, a0, 0, 0, 0);                      \
        a1 = MFMA(Am[1][0], BUF##m0, a1, 0, 0, 0);                      \
        a0 = MFMA(Ah[0][0], BUF##l0, a0, 0, 0, 0);                      \
        a1 = MFMA(Ah[1][0], BUF##l0, a1, 0, 0, 0);                      \
        a0 = MFMA(Al[0][0], BUF##h0, a0, 0, 0, 0);                      \
        a1 = MFMA(Al[1][0], BUF##h0, a1, 0, 0, 0);                      \
        a0 = MFMA(Am[0][0], BUF##h0, a0, 0, 0, 0);                      \
        a1 = MFMA(Am[1][0], BUF##h0, a1, 0, 0, 0);                      \
        a0 = MFMA(Ah[0][0], BUF##m0, a0, 0, 0, 0);                      \
        a1 = MFMA(Ah[1][0], BUF##m0, a1, 0, 0, 0);                      \
        a0 = MFMA(Ah[0][0], BUF##h0, a0, 0, 0, 0);                      \
        a1 = MFMA(Ah[1][0], BUF##h0, a1, 0, 0, 0);                      \
        a0 = MFMA(Am[0][1], BUF##m1, a0, 0, 0, 0);                      \
        a1 = MFMA(Am[1][1], BUF##m1, a1, 0, 0, 0);                      \
        a0 = MFMA(Ah[0][1], BUF##l1, a0, 0, 0, 0);                      \
        a1 = MFMA(Ah[1][1], BUF##l1, a1, 0, 0, 0);                      \
        a0 = MFMA(Al[0][1], BUF##h1, a0, 0, 0, 0);                      \
        a1 = MFMA(Al[1][1], BUF##h1, a1, 0, 0, 0);                      \
        a0 = MFMA(Am[0][1], BUF##h1, a0, 0, 0, 0);                      \
        a1 = MFMA(Am[1][1], BUF##h1, a1, 0, 0, 0);                      \
        a0 = MFMA(Ah[0][1], BUF##m1, a0, 0, 0, 0);                      \
        a1 = MFMA(Ah[1][1], BUF##m1, a1, 0, 0, 0);                      \
        a0 = MFMA(Ah[0][1], BUF##h1, a0, 0, 0, 0);                      \
        a1 = MFMA(Ah[1][1], BUF##h1, a1, 0, 0, 0);                      \
        a0 = MFMA(Am[0][2], BUF##m2, a0, 0, 0, 0);                      \
        a1 = MFMA(Am[1][2], BUF##m2, a1, 0, 0, 0);                      \
        a0 = MFMA(Ah[0][2], BUF##l2, a0, 0, 0, 0);                      \
        a1 = MFMA(Ah[1][2], BUF##l2, a1, 0, 0, 0);                      \
        a0 = MFMA(Al[0][2], BUF##h2, a0, 0, 0, 0);                      \
        a1 = MFMA(Al[1][2], BUF##h2, a1, 0, 0, 0);                      \
        a0 = MFMA(Am[0][2], BUF##h2, a0, 0, 0, 0);                      \
        a1 = MFMA(Am[1][2], BUF##h2, a1, 0, 0, 0);                      \
        a0 = MFMA(Ah[0][2], BUF##m2, a0, 0, 0, 0);                      \
        a1 = MFMA(Ah[1][2], BUF##m2, a1, 0, 0, 0);                      \
        a0 = MFMA(Ah[0][2], BUF##h2, a0, 0, 0, 0);                      \
        a1 = MFMA(Ah[1][2], BUF##h2, a1, 0, 0, 0);                      \
        const int kl_ = (T) * 32 + col;                                 \
        _Pragma("unroll")                                               \
        for (int q = 0; q < 16; ++q) {                                  \
            const float e0 = fmaf(a0[q], -2.0f, BUF##cn);               \
            if (e0 < best0[q]) { best0[q] = e0; bk0[q] = kl_; }         \
            const float e1 = fmaf(a1[q], -2.0f, BUF##cn);               \
            if (e1 < best1[q]) { best1[q] = e1; bk1[q] = kl_; }         \
        }                                                               \
    } while (0)

// Main: wave = 64 blocks (two 32x32 row-tiles) x all 1024 codes.
// fp32 GEMM emulated by 6 bf16 products; B double-buffered in registers.
__global__ __launch_bounds__(256, 2) void vq_mfma_kernel(const float* __restrict__ img,
                                                         const float* __restrict__ cb,
                                                         const float* __restrict__ ws,
                                                         float* __restrict__ out) {
    __shared__ int lds_bk[4 * 64];
    const int lane  = threadIdx.x & 63;
    const int wid   = threadIdx.x >> 6;
    const int wave  = blockIdx.x * 4 + wid;
    const int wbase = wave * 64;
    const int col = lane & 31, lh = lane >> 5;
    const float* cnorm = ws + WS_CNORM;
    const bf16x8* bfrag = (const bf16x8*)(ws + WS_BFRAG);

    // ---- load + split image A-fragments (VGPR-resident for whole K loop) ----
    bf16x8 Ah[2][3], Am[2][3], Al[2][3];
#pragma unroll
    for (int T = 0; T < 2; ++T) {
        const int b = wbase + T * 32 + col;
        const int by4 = (b >> 9) * 4, bx = b & 511;
#pragma unroll
        for (int s = 0; s < 3; ++s) {
            const int j0 = s * 16 + lh * 8;
            const int ja = j0, jb = j0 + 4;
            const int ra = (ja * 683) >> 13, ca = ja - 12 * ra;   // j/12, j%12
            const int rb = (jb * 683) >> 13, cb2 = jb - 12 * rb;
            const float4 fa = *(const float4*)(img + ((size_t)(by4 + ra) * 2048 + bx * 4) * 3 + ca);
            const float4 fb = *(const float4*)(img + ((size_t)(by4 + rb) * 2048 + bx * 4) * 3 + cb2);
            const float f[8] = {fa.x, fa.y, fa.z, fa.w, fb.x, fb.y, fb.z, fb.w};
#pragma unroll
            for (int e = 0; e < 8; ++e) {
                unsigned int hb, mb, lb;
                split3(f[e], hb, mb, lb);
                Ah[T][s][e] = (short)hb; Am[T][s][e] = (short)mb; Al[T][s][e] = (short)lb;
            }
        }
    }

    float best0[16], best1[16];
    int bk0[16], bk1[16];
#pragma unroll
    for (int q = 0; q < 16; ++q) { best0[q] = best1[q] = __builtin_inff(); bk0[q] = bk1[q] = 0; }

    // ---- K loop: manual 2x unroll, named ping-pong B buffers (prefetch) ----
    bf16x8 B0h0, B0h1, B0h2, B0m0, B0m1, B0m2, B0l0, B0l1, B0l2;
    bf16x8 B1h0, B1h1, B1h2, B1m0, B1m1, B1m2, B1l0, B1l1, B1l2;
    float B0cn, B1cn;

    LOADB(B0, 0);
#pragma unroll 1
    for (int t = 0; t < NTILE; t += 2) {
        LOADB(B1, t + 1);                                    // prefetch t+1
        COMPUTE(B0, t);
        LOADB(B0, (t + 2 < NTILE) ? t + 2 : NTILE - 1);      // prefetch t+2
        COMPUTE(B1, t + 1);
    }

    // ---- cross-lane lexicographic (d,k) reduce within each 32-lane half ----
#pragma unroll
    for (int q = 0; q < 16; ++q) {
        float d0 = best0[q]; int K0 = bk0[q];
        float d1 = best1[q]; int K1 = bk1[q];
#pragma unroll
        for (int m = 1; m < 32; m <<= 1) {
            float od = __shfl_xor(d0, m, 64); int ok = __shfl_xor(K0, m, 64);
            bool tk = (od < d0) || (od == d0 && ok < K0);
            d0 = tk ? od : d0; K0 = tk ? ok : K0;
            od = __shfl_xor(d1, m, 64); ok = __shfl_xor(K1, m, 64);
            tk = (od < d1) || (od == d1 && ok < K1);
            d1 = tk ? od : d1; K1 = tk ? ok : K1;
        }
        const int row32 = (q & 3) + 8 * (q >> 2) + 4 * lh;   // verified C-row map
        if ((lane & 31) == q) {
            lds_bk[wid * 64 + row32]      = K0;   // T=0 blocks
            lds_bk[wid * 64 + 32 + row32] = K1;   // T=1 blocks
        }
    }

    // ---- gather chosen code (fp32 original), scatter to image layout ----
    const int myk = lds_bk[wid * 64 + lane];     // block wbase+lane
    const int b = wbase + lane;
    const int by4 = (b >> 9) * 4, bx = b & 511;
    const float4* qp = (const float4*)(cb + (size_t)myk * DD);
#pragma unroll
    for (int r = 0; r < 4; ++r) {
        float4* op = (float4*)(out + ((size_t)(by4 + r) * 2048 + bx * 4) * 3);
        op[0] = qp[r * 3 + 0];
        op[1] = qp[r * 3 + 1];
        op[2] = qp[r * 3 + 2];
    }
}

extern "C" void kernel_launch(void* const* d_in, const int* in_sizes, int n_in,
                              void* d_out, int out_size, void* d_ws, size_t ws_size,
                              hipStream_t stream) {
    const float* img = (const float*)d_in[0];   // (2048, 2048, 3) fp32
    const float* cb  = (const float*)d_in[1];   // (1024, 16, 3) fp32
    float* out = (float*)d_out;                 // (2048, 2048, 3) fp32
    float* ws  = (float*)d_ws;

    vq_cnorm_kernel<<<(NK + 255) / 256, 256, 0, stream>>>(cb, ws + WS_CNORM);
    vq_bprep_kernel<<<(FRAGS_PER_LEVEL + 255) / 256, 256, 0, stream>>>(cb, ws);
    vq_mfma_kernel<<<NL / 64 / 4, 256, 0, stream>>>(img, cb, ws, out);
}

// Round 9
// 162.833 us; speedup vs baseline: 1.1841x; 1.1841x over previous
//
#include <hip/hip_runtime.h>

#define NK 1024
#define DD 48              // 4*4*3 floats per code / per block
#define NL (512 * 512)     // 262144 blocks
#define NTILE 32           // 32 code-tiles of 32 codes

// workspace layout (float offsets)
#define WS_CNORM 0
#define WS_BFRAG 1024
#define FRAGS_PER_LEVEL (32 * 3 * 64)     // tiles * ksteps * lanes = 6144 frags
#define WS_FLOATS (1024 + 3 * FRAGS_PER_LEVEL * 4)

typedef __attribute__((ext_vector_type(8)))  short bf16x8;
typedef __attribute__((ext_vector_type(16))) float f32x16;

// fp32 -> bf16 bits, round-to-nearest-even (finite inputs)
__device__ __forceinline__ unsigned int rneb(float x) {
    unsigned int u = __float_as_uint(x);
    return (u + 0x7FFFu + ((u >> 16) & 1u)) >> 16;
}
__device__ __forceinline__ float bftof(unsigned int b) {
    return __uint_as_float(b << 16);
}
// 3-term bf16 split: x = h + m + l (residual splits exact; l trunc ~2^-24 rel)
__device__ __forceinline__ void split3(float x, unsigned int& hb, unsigned int& mb, unsigned int& lb) {
    hb = rneb(x);
    float r1 = x - bftof(hb);
    mb = rneb(r1);
    float r2 = r1 - bftof(mb);
    lb = rneb(r2);
}

// cnorm[k] = sum_j cb[k][j]^2 (fp32 sequential FMA)
__global__ void vq_cnorm_kernel(const float* __restrict__ cb, float* __restrict__ cnorm) {
    int k = blockIdx.x * blockDim.x + threadIdx.x;
    if (k >= NK) return;
    const float* row = cb + k * DD;
    float s = 0.0f;
#pragma unroll
    for (int j = 0; j < DD; ++j) s = fmaf(row[j], row[j], s);
    cnorm[k] = s;
}

// B prep: pack codebook into MFMA B-fragments for levels h/m/l.
// Frag (t, s, lane): code = t*32 + (lane&31), j = s*16 + (lane>>5)*8 + e.
__global__ void vq_bprep_kernel(const float* __restrict__ cb, float* __restrict__ ws) {
    int tid = blockIdx.x * blockDim.x + threadIdx.x;
    if (tid >= FRAGS_PER_LEVEL) return;
    int lane = tid & 63;
    int s    = (tid >> 6) % 3;
    int t    = tid / (3 * 64);
    int col = lane & 31, lh = lane >> 5;
    int code = t * 32 + col;
    int j0 = s * 16 + lh * 8;
    const float* src = cb + code * DD + j0;
    bf16x8 vh, vm, vl;
#pragma unroll
    for (int e = 0; e < 8; ++e) {
        unsigned int hb, mb, lb;
        split3(src[e], hb, mb, lb);
        vh[e] = (short)hb; vm[e] = (short)mb; vl[e] = (short)lb;
    }
    bf16x8* base = (bf16x8*)(ws + WS_BFRAG);
    int fi = (t * 3 + s) * 64 + lane;
    base[0 * FRAGS_PER_LEVEL + fi] = vh;
    base[1 * FRAGS_PER_LEVEL + fi] = vm;
    base[2 * FRAGS_PER_LEVEL + fi] = vl;
}

#define MFMA __builtin_amdgcn_mfma_f32_32x32x16_bf16

// Main: wave = 64 blocks (two 32x32 row-tiles) x all 1024 codes.
// fp32 GEMM emulated by 6 bf16 products. 4 independent accumulator chains
// (2 per output tile: smalls {mm,hl,lh} and bigs {mh,hm,hh}) to cover MFMA
// dependent-issue latency; merged by one vector add before the min-update.
__global__ __launch_bounds__(256, 2) void vq_mfma_kernel(const float* __restrict__ img,
                                                         const float* __restrict__ cb,
                                                         const float* __restrict__ ws,
                                                         float* __restrict__ out) {
    __shared__ int lds_bk[4 * 64];
    const int lane  = threadIdx.x & 63;
    const int wid   = threadIdx.x >> 6;
    const int wave  = blockIdx.x * 4 + wid;
    const int wbase = wave * 64;
    const int col = lane & 31, lh = lane >> 5;
    const float* cnorm = ws + WS_CNORM;
    const bf16x8* bfrag = (const bf16x8*)(ws + WS_BFRAG);

    // ---- load + split image A-fragments (VGPR-resident for whole K loop) ----
    bf16x8 Ah[2][3], Am[2][3], Al[2][3];
#pragma unroll
    for (int T = 0; T < 2; ++T) {
        const int b = wbase + T * 32 + col;
        const int by4 = (b >> 9) * 4, bx = b & 511;
#pragma unroll
        for (int s = 0; s < 3; ++s) {
            const int j0 = s * 16 + lh * 8;
            const int ja = j0, jb = j0 + 4;
            const int ra = (ja * 683) >> 13, ca = ja - 12 * ra;   // j/12, j%12
            const int rb = (jb * 683) >> 13, cb2 = jb - 12 * rb;
            const float4 fa = *(const float4*)(img + ((size_t)(by4 + ra) * 2048 + bx * 4) * 3 + ca);
            const float4 fb = *(const float4*)(img + ((size_t)(by4 + rb) * 2048 + bx * 4) * 3 + cb2);
            const float f[8] = {fa.x, fa.y, fa.z, fa.w, fb.x, fb.y, fb.z, fb.w};
#pragma unroll
            for (int e = 0; e < 8; ++e) {
                unsigned int hb, mb, lb;
                split3(f[e], hb, mb, lb);
                Ah[T][s][e] = (short)hb; Am[T][s][e] = (short)mb; Al[T][s][e] = (short)lb;
            }
        }
    }

    float best0[16], best1[16];
    int bk0[16], bk1[16];
#pragma unroll
    for (int q = 0; q < 16; ++q) { best0[q] = best1[q] = __builtin_inff(); bk0[q] = bk1[q] = 0; }

#pragma unroll 1
    for (int t = 0; t < NTILE; ++t) {
        bf16x8 Bh[3], Bm[3], Bl[3];
#pragma unroll
        for (int s = 0; s < 3; ++s) {
            const int fi = (t * 3 + s) * 64 + lane;
            Bh[s] = bfrag[fi];
            Bm[s] = bfrag[FRAGS_PER_LEVEL + fi];
            Bl[s] = bfrag[2 * FRAGS_PER_LEVEL + fi];
        }
        const float cn = cnorm[t * 32 + col];
        const int   kl = t * 32 + col;

        // 4 independent accumulator chains (dep distance = 4 MFMAs)
        f32x16 a0a, a0b, a1a, a1b;
#pragma unroll
        for (int q = 0; q < 16; ++q) { a0a[q] = 0.0f; a0b[q] = 0.0f; a1a[q] = 0.0f; a1b[q] = 0.0f; }

#pragma unroll
        for (int s = 0; s < 3; ++s) {
            a0a = MFMA(Am[0][s], Bm[s], a0a, 0, 0, 0);   // smalls chain, T=0
            a1a = MFMA(Am[1][s], Bm[s], a1a, 0, 0, 0);   // smalls chain, T=1
            a0b = MFMA(Am[0][s], Bh[s], a0b, 0, 0, 0);   // bigs chain, T=0
            a1b = MFMA(Am[1][s], Bh[s], a1b, 0, 0, 0);   // bigs chain, T=1
            a0a = MFMA(Ah[0][s], Bl[s], a0a, 0, 0, 0);
            a1a = MFMA(Ah[1][s], Bl[s], a1a, 0, 0, 0);
            a0b = MFMA(Ah[0][s], Bm[s], a0b, 0, 0, 0);
            a1b = MFMA(Ah[1][s], Bm[s], a1b, 0, 0, 0);
            a0a = MFMA(Al[0][s], Bh[s], a0a, 0, 0, 0);
            a1a = MFMA(Al[1][s], Bh[s], a1a, 0, 0, 0);
            a0b = MFMA(Ah[0][s], Bh[s], a0b, 0, 0, 0);
            a1b = MFMA(Ah[1][s], Bh[s], a1b, 0, 0, 0);
        }

        // merge chains (smalls + bigs), then e = -2*dot + cn, min-update
#pragma unroll
        for (int q = 0; q < 16; ++q) {
            const float s0 = a0a[q] + a0b[q];
            const float e0 = fmaf(s0, -2.0f, cn);
            if (e0 < best0[q]) { best0[q] = e0; bk0[q] = kl; }
            const float s1 = a1a[q] + a1b[q];
            const float e1 = fmaf(s1, -2.0f, cn);
            if (e1 < best1[q]) { best1[q] = e1; bk1[q] = kl; }
        }
    }

    // ---- cross-lane lexicographic (d,k) reduce within each 32-lane half ----
#pragma unroll
    for (int q = 0; q < 16; ++q) {
        float d0 = best0[q]; int K0 = bk0[q];
        float d1 = best1[q]; int K1 = bk1[q];
#pragma unroll
        for (int m = 1; m < 32; m <<= 1) {
            float od = __shfl_xor(d0, m, 64); int ok = __shfl_xor(K0, m, 64);
            bool tk = (od < d0) || (od == d0 && ok < K0);
            d0 = tk ? od : d0; K0 = tk ? ok : K0;
            od = __shfl_xor(d1, m, 64); ok = __shfl_xor(K1, m, 64);
            tk = (od < d1) || (od == d1 && ok < K1);
            d1 = tk ? od : d1; K1 = tk ? ok : K1;
        }
        const int row32 = (q & 3) + 8 * (q >> 2) + 4 * lh;   // verified C-row map
        if ((lane & 31) == q) {
            lds_bk[wid * 64 + row32]      = K0;   // T=0 blocks
            lds_bk[wid * 64 + 32 + row32] = K1;   // T=1 blocks
        }
    }

    // ---- gather chosen code (fp32 original), scatter to image layout ----
    const int myk = lds_bk[wid * 64 + lane];     // block wbase+lane
    const int b = wbase + lane;
    const int by4 = (b >> 9) * 4, bx = b & 511;
    const float4* qp = (const float4*)(cb + (size_t)myk * DD);
#pragma unroll
    for (int r = 0; r < 4; ++r) {
        float4* op = (float4*)(out + ((size_t)(by4 + r) * 2048 + bx * 4) * 3);
        op[0] = qp[r * 3 + 0];
        op[1] = qp[r * 3 + 1];
        op[2] = qp[r * 3 + 2];
    }
}

extern "C" void kernel_launch(void* const* d_in, const int* in_sizes, int n_in,
                              void* d_out, int out_size, void* d_ws, size_t ws_size,
                              hipStream_t stream) {
    const float* img = (const float*)d_in[0];   // (2048, 2048, 3) fp32
    const float* cb  = (const float*)d_in[1];   // (1024, 16, 3) fp32
    float* out = (float*)d_out;                 // (2048, 2048, 3) fp32
    float* ws  = (float*)d_ws;

    vq_cnorm_kernel<<<(NK + 255) / 256, 256, 0, stream>>>(cb, ws + WS_CNORM);
    vq_bprep_kernel<<<(FRAGS_PER_LEVEL + 255) / 256, 256, 0, stream>>>(cb, ws);
    vq_mfma_kernel<<<NL / 64 / 4, 256, 0, stream>>>(img, cb, ws, out);
}

// Round 10
// 140.051 us; speedup vs baseline: 1.3767x; 1.1627x over previous
//
#include <hip/hip_runtime.h>

#define NK 1024
#define DD 48              // 4*4*3 floats per code / per block
#define NL (512 * 512)     // 262144 blocks
#define NTILE 32           // 32 code-tiles of 32 codes

// workspace layout (float offsets)
#define WS_CNORM 0
#define WS_BFRAG 1024
#define FRAGS (32 * 3 * 64)     // tiles * ksteps * lanes = 6144 frags per level

typedef __attribute__((ext_vector_type(8)))  _Float16 half8;
typedef __attribute__((ext_vector_type(16))) float    f32x16;

// fp16 2-split: x = h + m*2^-12, m stored scaled by 4096 (fp16-normal range).
// Truncation l <= 2^-24|x| -- below the fp32 accumulation noise floor.
__device__ __forceinline__ void split2(float x, _Float16& h, _Float16& m) {
    h = (_Float16)x;
    const float r = x - (float)h;          // exact (Sterbenz-class)
    m = (_Float16)(r * 4096.0f);           // exact scale; RN to fp16
}

// cnorm[k] = sum_j cb[k][j]^2 (fp32 sequential FMA)
__global__ void vq_cnorm_kernel(const float* __restrict__ cb, float* __restrict__ cnorm) {
    int k = blockIdx.x * blockDim.x + threadIdx.x;
    if (k >= NK) return;
    const float* row = cb + k * DD;
    float s = 0.0f;
#pragma unroll
    for (int j = 0; j < DD; ++j) s = fmaf(row[j], row[j], s);
    cnorm[k] = s;
}

// B prep: pack codebook into fp16 MFMA B-fragments, levels h and m' (x4096).
// Frag (t, s, lane): code = t*32 + (lane&31), j = s*16 + (lane>>5)*8 + e.
__global__ void vq_bprep_kernel(const float* __restrict__ cb, float* __restrict__ ws) {
    int tid = blockIdx.x * blockDim.x + threadIdx.x;
    if (tid >= FRAGS) return;
    int lane = tid & 63;
    int s    = (tid >> 6) % 3;
    int t    = tid / (3 * 64);
    int col = lane & 31, lh = lane >> 5;
    const float* src = cb + (t * 32 + col) * DD + s * 16 + lh * 8;
    half8 vh, vm;
#pragma unroll
    for (int e = 0; e < 8; ++e) {
        _Float16 h, m;
        split2(src[e], h, m);
        vh[e] = h; vm[e] = m;
    }
    half8* base = (half8*)(ws + WS_BFRAG);
    int fi = (t * 3 + s) * 64 + lane;
    base[fi]         = vh;
    base[FRAGS + fi] = vm;
}

#define MFMA16 __builtin_amdgcn_mfma_f32_32x32x16_f16

// Main: wave = 32 blocks (ONE 32x32 tile) x all 1024 codes.
// fp32 GEMM emulated by 4 fp16 products (hh, hm', m'h, m'm') in 4 scale-
// separated accumulator chains (dep distance 4 MFMAs = 129 cy).
__global__ __launch_bounds__(256, 3) void vq_mfma_kernel(const float* __restrict__ img,
                                                         const float* __restrict__ cb,
                                                         const float* __restrict__ ws,
                                                         float* __restrict__ out) {
    __shared__ int lds_bk[4 * 32];
    const int lane  = threadIdx.x & 63;
    const int wid   = threadIdx.x >> 6;
    const int wave  = blockIdx.x * 4 + wid;
    const int wbase = wave * 32;
    const int col = lane & 31, lh = lane >> 5;
    const float* cnorm = ws + WS_CNORM;
    const half8* bfrag = (const half8*)(ws + WS_BFRAG);

    // ---- load + split this wave's 32 image blocks into A-fragments ----
    half8 Ah[3], Am[3];
    {
        const int b = wbase + col;
        const int by4 = (b >> 9) * 4, bx = b & 511;
#pragma unroll
        for (int s = 0; s < 3; ++s) {
            const int j0 = s * 16 + lh * 8;
            const int ja = j0, jb = j0 + 4;
            const int ra = (ja * 683) >> 13, ca = ja - 12 * ra;   // j/12, j%12
            const int rb = (jb * 683) >> 13, cb2 = jb - 12 * rb;
            const float4 fa = *(const float4*)(img + ((size_t)(by4 + ra) * 2048 + bx * 4) * 3 + ca);
            const float4 fb = *(const float4*)(img + ((size_t)(by4 + rb) * 2048 + bx * 4) * 3 + cb2);
            const float f[8] = {fa.x, fa.y, fa.z, fa.w, fb.x, fb.y, fb.z, fb.w};
#pragma unroll
            for (int e = 0; e < 8; ++e) {
                _Float16 h, m;
                split2(f[e], h, m);
                Ah[s][e] = h; Am[s][e] = m;
            }
        }
    }

    float best[16];
    int bk[16];
#pragma unroll
    for (int q = 0; q < 16; ++q) { best[q] = __builtin_inff(); bk[q] = 0; }

#pragma unroll 1
    for (int t = 0; t < NTILE; ++t) {
        half8 Bh[3], Bm[3];
#pragma unroll
        for (int s = 0; s < 3; ++s) {
            const int fi = (t * 3 + s) * 64 + lane;
            Bh[s] = bfrag[fi];
            Bm[s] = bfrag[FRAGS + fi];
        }
        const float cn = cnorm[t * 32 + col];
        const int   kl = t * 32 + col;

        // 4 scale-separated chains: c1=hh (x1), c2a=hm', c2b=m'h (x2^-12),
        // c3=m'm' (x2^-24). Round-robin -> dep distance 4 MFMAs.
        f32x16 c1, c2a, c2b, c3;
#pragma unroll
        for (int q = 0; q < 16; ++q) { c1[q] = 0.0f; c2a[q] = 0.0f; c2b[q] = 0.0f; c3[q] = 0.0f; }

#pragma unroll
        for (int s = 0; s < 3; ++s) {
            c1  = MFMA16(Ah[s], Bh[s], c1,  0, 0, 0);
            c2a = MFMA16(Ah[s], Bm[s], c2a, 0, 0, 0);
            c2b = MFMA16(Am[s], Bh[s], c2b, 0, 0, 0);
            c3  = MFMA16(Am[s], Bm[s], c3,  0, 0, 0);
        }

        // merge scales, then e = -2*dot + cn, strict-< first-occurrence min
#pragma unroll
        for (int q = 0; q < 16; ++q) {
            const float t2  = c2a[q] + c2b[q];
            float dot = fmaf(t2, 0x1p-12f, c1[q]);
            dot = fmaf(c3[q], 0x1p-24f, dot);
            const float e = fmaf(dot, -2.0f, cn);
            if (e < best[q]) { best[q] = e; bk[q] = kl; }
        }
    }

    // ---- cross-lane lexicographic (d,k) reduce within each 32-lane half ----
#pragma unroll
    for (int q = 0; q < 16; ++q) {
        float d = best[q]; int K = bk[q];
#pragma unroll
        for (int m = 1; m < 32; m <<= 1) {
            const float od = __shfl_xor(d, m, 64);
            const int   ok = __shfl_xor(K, m, 64);
            const bool tk = (od < d) || (od == d && ok < K);
            d = tk ? od : d; K = tk ? ok : K;
        }
        const int row32 = (q & 3) + 8 * (q >> 2) + 4 * lh;   // verified C-row map
        if ((lane & 31) == q) lds_bk[wid * 32 + row32] = K;
    }
    __syncthreads();

    // ---- gather chosen code (fp32 original), scatter to image layout ----
    // lane handles block wbase+col, image rows {2*lh, 2*lh+1} of the block.
    const int myk = lds_bk[wid * 32 + col];
    const int b = wbase + col;
    const int by4 = (b >> 9) * 4, bx = b & 511;
    const float4* qp = (const float4*)(cb + (size_t)myk * DD);
#pragma unroll
    for (int rr = 0; rr < 2; ++rr) {
        const int r = lh * 2 + rr;
        float4* op = (float4*)(out + ((size_t)(by4 + r) * 2048 + bx * 4) * 3);
        op[0] = qp[r * 3 + 0];
        op[1] = qp[r * 3 + 1];
        op[2] = qp[r * 3 + 2];
    }
}

extern "C" void kernel_launch(void* const* d_in, const int* in_sizes, int n_in,
                              void* d_out, int out_size, void* d_ws, size_t ws_size,
                              hipStream_t stream) {
    const float* img = (const float*)d_in[0];   // (2048, 2048, 3) fp32
    const float* cb  = (const float*)d_in[1];   // (1024, 16, 3) fp32
    float* out = (float*)d_out;                 // (2048, 2048, 3) fp32
    float* ws  = (float*)d_ws;

    vq_cnorm_kernel<<<(NK + 255) / 256, 256, 0, stream>>>(cb, ws + WS_CNORM);
    vq_bprep_kernel<<<(FRAGS + 255) / 256, 256, 0, stream>>>(cb, ws);
    vq_mfma_kernel<<<NL / 32 / 4, 256, 0, stream>>>(img, cb, ws, out);
}

// Round 11
// 137.231 us; speedup vs baseline: 1.4050x; 1.0206x over previous
//
#include <hip/hip_runtime.h>

#define NK 1024
#define DD 48              // 4*4*3 floats per code / per block
#define NL (512 * 512)     // 262144 blocks
#define NTILE 32           // 32 code-tiles of 32 codes

// workspace layout (float offsets)
#define WS_CNH 0           // -0.5*cnorm[k]
#define WS_BFRAG 1024
#define NFRAG_TIDS (32 * 3 * 64)   // bprep threads: tiles * ksteps * lanes

typedef __attribute__((ext_vector_type(8)))  _Float16 half8;
typedef __attribute__((ext_vector_type(16))) float    f32x16;

// fp16 2-split: x = h + m*2^-12, m stored scaled by 4096 (fp16-normal range).
__device__ __forceinline__ void split2(float x, _Float16& h, _Float16& m) {
    h = (_Float16)x;
    const float r = x - (float)h;          // exact
    m = (_Float16)(r * 4096.0f);           // exact scale; RN to fp16
}

// cnh[k] = -0.5 * sum_j cb[k][j]^2 (fp32 sequential FMA; *0.5 exact)
__global__ void vq_cnorm_kernel(const float* __restrict__ cb, float* __restrict__ cnh) {
    int k = blockIdx.x * blockDim.x + threadIdx.x;
    if (k >= NK) return;
    const float* row = cb + k * DD;
    float s = 0.0f;
#pragma unroll
    for (int j = 0; j < DD; ++j) s = fmaf(row[j], row[j], s);
    cnh[k] = -0.5f * s;
}

// B prep: tile-major fragment layout. For tile t:
//   frag[(t*6 + s)*64 + lane]     = h-level, kstep s
//   frag[(t*6 + 3 + s)*64 + lane] = m'-level, kstep s
// code = t*32 + (lane&31), j = s*16 + (lane>>5)*8 + e.
__global__ void vq_bprep_kernel(const float* __restrict__ cb, float* __restrict__ ws) {
    int tid = blockIdx.x * blockDim.x + threadIdx.x;
    if (tid >= NFRAG_TIDS) return;
    int lane = tid & 63;
    int s    = (tid >> 6) % 3;
    int t    = tid / (3 * 64);
    int col = lane & 31, lh = lane >> 5;
    const float* src = cb + (t * 32 + col) * DD + s * 16 + lh * 8;
    half8 vh, vm;
#pragma unroll
    for (int e = 0; e < 8; ++e) {
        _Float16 h, m;
        split2(src[e], h, m);
        vh[e] = h; vm[e] = m;
    }
    half8* base = (half8*)(ws + WS_BFRAG);
    base[(t * 6 + s) * 64 + lane]     = vh;
    base[(t * 6 + 3 + s) * 64 + lane] = vm;
}

#define MFMA16 __builtin_amdgcn_mfma_f32_32x32x16_f16

// Main: wave = 32 blocks (one 32x32 tile) x all 1024 codes.
// fp32 GEMM emulated by 4 fp16 products in 3 scale-separated chains:
//   c1 = hh  (init -cn/2: embeds the codebook norm)
//   c2 = hm' + m'h  (x 2^-12)
//   c3 = m'm'       (x 2^-24)
// argmin(d2) == argmax(m = dot - cn/2), strict-> keeps first occurrence.
__global__ __launch_bounds__(256, 3) void vq_mfma_kernel(const float* __restrict__ img,
                                                         const float* __restrict__ cb,
                                                         const float* __restrict__ ws,
                                                         float* __restrict__ out) {
    __shared__ int lds_bk[4 * 32];
    const int lane  = threadIdx.x & 63;
    const int wid   = threadIdx.x >> 6;
    const int wave  = blockIdx.x * 4 + wid;
    const int wbase = wave * 32;
    const int col = lane & 31, lh = lane >> 5;
    const float* cnp  = ws + WS_CNH + col;              // -cn/2 stream
    const half8* bp   = (const half8*)(ws + WS_BFRAG) + lane;

    // ---- load + split this wave's 32 image blocks into A-fragments ----
    half8 Ah[3], Am[3];
    {
        const int b = wbase + col;
        const int by4 = (b >> 9) * 4, bx = b & 511;
#pragma unroll
        for (int s = 0; s < 3; ++s) {
            const int j0 = s * 16 + lh * 8;
            const int ja = j0, jb = j0 + 4;
            const int ra = (ja * 683) >> 13, ca = ja - 12 * ra;   // j/12, j%12
            const int rb = (jb * 683) >> 13, cb2 = jb - 12 * rb;
            const float4 fa = *(const float4*)(img + ((size_t)(by4 + ra) * 2048 + bx * 4) * 3 + ca);
            const float4 fb = *(const float4*)(img + ((size_t)(by4 + rb) * 2048 + bx * 4) * 3 + cb2);
            const float f[8] = {fa.x, fa.y, fa.z, fa.w, fb.x, fb.y, fb.z, fb.w};
#pragma unroll
            for (int e = 0; e < 8; ++e) {
                _Float16 h, m;
                split2(f[e], h, m);
                Ah[s][e] = h; Am[s][e] = m;
            }
        }
    }

    f32x16 best;
    int bk[16];
#pragma unroll
    for (int q = 0; q < 16; ++q) { best[q] = -__builtin_inff(); bk[q] = 0; }

#pragma unroll 1
    for (int t = 0; t < NTILE; ++t) {
        const half8* pt = bp + t * 384;          // 6 frags, imm offsets
        const half8 Bh0 = pt[0],   Bh1 = pt[64],  Bh2 = pt[128];
        const half8 Bm0 = pt[192], Bm1 = pt[256], Bm2 = pt[320];
        const float cnh2 = cnp[t * 32];          // -cn/2
        const int   kl   = t * 32 + col;

        f32x16 c1, c2, c3;
#pragma unroll
        for (int q = 0; q < 16; ++q) { c1[q] = cnh2; c2[q] = 0.0f; c3[q] = 0.0f; }

        c1 = MFMA16(Ah[0], Bh0, c1, 0, 0, 0);
        c2 = MFMA16(Ah[0], Bm0, c2, 0, 0, 0);
        c3 = MFMA16(Am[0], Bm0, c3, 0, 0, 0);
        c2 = MFMA16(Am[0], Bh0, c2, 0, 0, 0);
        c1 = MFMA16(Ah[1], Bh1, c1, 0, 0, 0);
        c2 = MFMA16(Ah[1], Bm1, c2, 0, 0, 0);
        c3 = MFMA16(Am[1], Bm1, c3, 0, 0, 0);
        c2 = MFMA16(Am[1], Bh1, c2, 0, 0, 0);
        c1 = MFMA16(Ah[2], Bh2, c1, 0, 0, 0);
        c2 = MFMA16(Ah[2], Bm2, c2, 0, 0, 0);
        c3 = MFMA16(Am[2], Bm2, c3, 0, 0, 0);
        c2 = MFMA16(Am[2], Bh2, c2, 0, 0, 0);

        // vector merge (packed fp32 ops): m = c1 + c2*2^-12 + c3*2^-24
        f32x16 m = c2 * 0x1p-12f + c1;
        m = c3 * 0x1p-24f + m;

        // bk select (scalar cmp+cndmask), then packed max update
#pragma unroll
        for (int q = 0; q < 16; ++q) if (m[q] > best[q]) bk[q] = kl;
#pragma unroll
        for (int q = 0; q < 16; ++q) best[q] = fmaxf(best[q], m[q]);
    }

    // ---- cross-lane lexicographic (max m, min k) reduce over 32 cols ----
#pragma unroll
    for (int q = 0; q < 16; ++q) {
        float d = best[q]; int K = bk[q];
#pragma unroll
        for (int mm = 1; mm < 32; mm <<= 1) {
            const float od = __shfl_xor(d, mm, 64);
            const int   ok = __shfl_xor(K, mm, 64);
            const bool tk = (od > d) || (od == d && ok < K);
            d = tk ? od : d; K = tk ? ok : K;
        }
        const int row32 = (q & 3) + 8 * (q >> 2) + 4 * lh;   // verified C-row map
        if ((lane & 31) == q) lds_bk[wid * 32 + row32] = K;
    }
    __syncthreads();

    // ---- gather chosen code (fp32 original), scatter to image layout ----
    const int myk = lds_bk[wid * 32 + col];
    const int b = wbase + col;
    const int by4 = (b >> 9) * 4, bx = b & 511;
    const float4* qp = (const float4*)(cb + (size_t)myk * DD);
#pragma unroll
    for (int rr = 0; rr < 2; ++rr) {
        const int r = lh * 2 + rr;
        float4* op = (float4*)(out + ((size_t)(by4 + r) * 2048 + bx * 4) * 3);
        op[0] = qp[r * 3 + 0];
        op[1] = qp[r * 3 + 1];
        op[2] = qp[r * 3 + 2];
    }
}

extern "C" void kernel_launch(void* const* d_in, const int* in_sizes, int n_in,
                              void* d_out, int out_size, void* d_ws, size_t ws_size,
                              hipStream_t stream) {
    const float* img = (const float*)d_in[0];   // (2048, 2048, 3) fp32
    const float* cb  = (const float*)d_in[1];   // (1024, 16, 3) fp32
    float* out = (float*)d_out;                 // (2048, 2048, 3) fp32
    float* ws  = (float*)d_ws;

    vq_cnorm_kernel<<<(NK + 255) / 256, 256, 0, stream>>>(cb, ws + WS_CNH);
    vq_bprep_kernel<<<(NFRAG_TIDS + 255) / 256, 256, 0, stream>>>(cb, ws);
    vq_mfma_kernel<<<NL / 32 / 4, 256, 0, stream>>>(img, cb, ws, out);
}

// Round 12
// 118.215 us; speedup vs baseline: 1.6311x; 1.1609x over previous
//
#include <hip/hip_runtime.h>

#define NK 1024
#define DD 48              // 4*4*3 floats per code / per block
#define NL (512 * 512)     // 262144 blocks
#define NTILE 32           // 32 code-tiles of 32 codes

// workspace layout (float offsets)
#define WS_CNH 0           // -0.5*cnorm[k]
#define WS_BFRAG 1024
#define NFRAG_TIDS (32 * 3 * 64)   // bprep threads: tiles * ksteps * lanes

typedef __attribute__((ext_vector_type(8)))  _Float16 half8;
typedef __attribute__((ext_vector_type(16))) float    f32x16;

// fp16 2-split: x = h + m*2^-12, m stored scaled by 4096 (fp16-normal range).
__device__ __forceinline__ void split2(float x, _Float16& h, _Float16& m) {
    h = (_Float16)x;
    const float r = x - (float)h;          // exact
    m = (_Float16)(r * 4096.0f);           // exact scale; RN to fp16
}

// cnh[k] = -0.5 * sum_j cb[k][j]^2 (fp32 sequential FMA; *0.5 exact)
__global__ void vq_cnorm_kernel(const float* __restrict__ cb, float* __restrict__ cnh) {
    int k = blockIdx.x * blockDim.x + threadIdx.x;
    if (k >= NK) return;
    const float* row = cb + k * DD;
    float s = 0.0f;
#pragma unroll
    for (int j = 0; j < DD; ++j) s = fmaf(row[j], row[j], s);
    cnh[k] = -0.5f * s;
}

// B prep: tile-major fragment layout. For tile t:
//   frag[(t*6 + s)*64 + lane]     = h-level, kstep s
//   frag[(t*6 + 3 + s)*64 + lane] = m'-level, kstep s
// code = t*32 + (lane&31), j = s*16 + (lane>>5)*8 + e.
__global__ void vq_bprep_kernel(const float* __restrict__ cb, float* __restrict__ ws) {
    int tid = blockIdx.x * blockDim.x + threadIdx.x;
    if (tid >= NFRAG_TIDS) return;
    int lane = tid & 63;
    int s    = (tid >> 6) % 3;
    int t    = tid / (3 * 64);
    int col = lane & 31, lh = lane >> 5;
    const float* src = cb + (t * 32 + col) * DD + s * 16 + lh * 8;
    half8 vh, vm;
#pragma unroll
    for (int e = 0; e < 8; ++e) {
        _Float16 h, m;
        split2(src[e], h, m);
        vh[e] = h; vm[e] = m;
    }
    half8* base = (half8*)(ws + WS_BFRAG);
    base[(t * 6 + s) * 64 + lane]     = vh;
    base[(t * 6 + 3 + s) * 64 + lane] = vm;
}

#define MFMA16 __builtin_amdgcn_mfma_f32_32x32x16_f16

// Main: wave = 32 blocks (one 32x32 tile) x all 1024 codes.
// fp32 GEMM emulated by 3 fp16 products in 2 scale-separated chains:
//   c1 = hh            (init -cn/2: embeds the codebook norm)
//   c2 = hm' + m'h     (x 2^-12)
// (m'm' dropped: RMS ~3e-7 on the dot, below the validated fp16-truncation
//  noise floor that flipped zero argmins in R10/R11.)
// argmin(d2) == argmax(m = dot - cn/2), strict-> keeps first occurrence.
__global__ __launch_bounds__(256, 4) void vq_mfma_kernel(const float* __restrict__ img,
                                                         const float* __restrict__ cb,
                                                         const float* __restrict__ ws,
                                                         float* __restrict__ out) {
    __shared__ int lds_bk[4 * 32];
    const int lane  = threadIdx.x & 63;
    const int wid   = threadIdx.x >> 6;
    const int wave  = blockIdx.x * 4 + wid;
    const int wbase = wave * 32;
    const int col = lane & 31, lh = lane >> 5;
    const float* cnp  = ws + WS_CNH + col;              // -cn/2 stream
    const half8* bp   = (const half8*)(ws + WS_BFRAG) + lane;

    // ---- load + split this wave's 32 image blocks into A-fragments ----
    half8 Ah[3], Am[3];
    {
        const int b = wbase + col;
        const int by4 = (b >> 9) * 4, bx = b & 511;
#pragma unroll
        for (int s = 0; s < 3; ++s) {
            const int j0 = s * 16 + lh * 8;
            const int ja = j0, jb = j0 + 4;
            const int ra = (ja * 683) >> 13, ca = ja - 12 * ra;   // j/12, j%12
            const int rb = (jb * 683) >> 13, cb2 = jb - 12 * rb;
            const float4 fa = *(const float4*)(img + ((size_t)(by4 + ra) * 2048 + bx * 4) * 3 + ca);
            const float4 fb = *(const float4*)(img + ((size_t)(by4 + rb) * 2048 + bx * 4) * 3 + cb2);
            const float f[8] = {fa.x, fa.y, fa.z, fa.w, fb.x, fb.y, fb.z, fb.w};
#pragma unroll
            for (int e = 0; e < 8; ++e) {
                _Float16 h, m;
                split2(f[e], h, m);
                Ah[s][e] = h; Am[s][e] = m;
            }
        }
    }

    f32x16 best;
    int bk[16];
#pragma unroll
    for (int q = 0; q < 16; ++q) { best[q] = -__builtin_inff(); bk[q] = 0; }

#pragma unroll 1
    for (int t = 0; t < NTILE; ++t) {
        const half8* pt = bp + t * 384;          // 6 frags, imm offsets
        const half8 Bh0 = pt[0],   Bh1 = pt[64],  Bh2 = pt[128];
        const half8 Bm0 = pt[192], Bm1 = pt[256], Bm2 = pt[320];
        const float cnh2 = cnp[t * 32];          // -cn/2
        const int   kl   = t * 32 + col;

        f32x16 c1, c2;
#pragma unroll
        for (int q = 0; q < 16; ++q) { c1[q] = cnh2; c2[q] = 0.0f; }

        c2 = MFMA16(Ah[0], Bm0, c2, 0, 0, 0);
        c1 = MFMA16(Ah[0], Bh0, c1, 0, 0, 0);
        c2 = MFMA16(Am[0], Bh0, c2, 0, 0, 0);
        c2 = MFMA16(Ah[1], Bm1, c2, 0, 0, 0);
        c1 = MFMA16(Ah[1], Bh1, c1, 0, 0, 0);
        c2 = MFMA16(Am[1], Bh1, c2, 0, 0, 0);
        c2 = MFMA16(Ah[2], Bm2, c2, 0, 0, 0);
        c1 = MFMA16(Ah[2], Bh2, c1, 0, 0, 0);
        c2 = MFMA16(Am[2], Bh2, c2, 0, 0, 0);

        // vector merge (packed fp32): m = c1 + c2*2^-12
        const f32x16 m = c2 * 0x1p-12f + c1;

        // bk select (scalar cmp+cndmask), then packed max update
#pragma unroll
        for (int q = 0; q < 16; ++q) if (m[q] > best[q]) bk[q] = kl;
#pragma unroll
        for (int q = 0; q < 16; ++q) best[q] = fmaxf(best[q], m[q]);
    }

    // ---- cross-lane lexicographic (max m, min k) reduce over 32 cols ----
#pragma unroll
    for (int q = 0; q < 16; ++q) {
        float d = best[q]; int K = bk[q];
#pragma unroll
        for (int mm = 1; mm < 32; mm <<= 1) {
            const float od = __shfl_xor(d, mm, 64);
            const int   ok = __shfl_xor(K, mm, 64);
            const bool tk = (od > d) || (od == d && ok < K);
            d = tk ? od : d; K = tk ? ok : K;
        }
        const int row32 = (q & 3) + 8 * (q >> 2) + 4 * lh;   // verified C-row map
        if ((lane & 31) == q) lds_bk[wid * 32 + row32] = K;
    }
    __syncthreads();

    // ---- gather chosen code (fp32 original), scatter to image layout ----
    const int myk = lds_bk[wid * 32 + col];
    const int b = wbase + col;
    const int by4 = (b >> 9) * 4, bx = b & 511;
    const float4* qp = (const float4*)(cb + (size_t)myk * DD);
#pragma unroll
    for (int rr = 0; rr < 2; ++rr) {
        const int r = lh * 2 + rr;
        float4* op = (float4*)(out + ((size_t)(by4 + r) * 2048 + bx * 4) * 3);
        op[0] = qp[r * 3 + 0];
        op[1] = qp[r * 3 + 1];
        op[2] = qp[r * 3 + 2];
    }
}

extern "C" void kernel_launch(void* const* d_in, const int* in_sizes, int n_in,
                              void* d_out, int out_size, void* d_ws, size_t ws_size,
                              hipStream_t stream) {
    const float* img = (const float*)d_in[0];   // (2048, 2048, 3) fp32
    const float* cb  = (const float*)d_in[1];   // (1024, 16, 3) fp32
    float* out = (float*)d_out;                 // (2048, 2048, 3) fp32
    float* ws  = (float*)d_ws;

    vq_cnorm_kernel<<<(NK + 255) / 256, 256, 0, stream>>>(cb, ws + WS_CNH);
    vq_bprep_kernel<<<(NFRAG_TIDS + 255) / 256, 256, 0, stream>>>(cb, ws);
    vq_mfma_kernel<<<NL / 32 / 4, 256, 0, stream>>>(img, cb, ws, out);
}